// Round 2
// baseline (62.419 us; speedup 1.0000x reference)
//
#include <hip/hip_runtime.h>
#include <math.h>

// Histogram-equalization L2 loss, 3 channels, K=256 bins, N_PIX=224*224.
// Faithful port of the JAX reference:
//   cum = floor(cumsum_f32(hist)); s = searchsorted_right(cum, p)
//   h[p] = (s == 255) ? h_prev[p] : min(s, 255)     (carry across channels)
//   loss = sum_ch sqrt(sum_p (h1-h2)^2)
// All sums exact integer; cumsum strictly sequential f32 to match reference
// rounding order.

#define N_PIX 50176
#define KBINS 256
#define PAD 257  // +1 pad: six 256-int tables would otherwise alias banks

// Branchless count of elements <= p in sorted 256-int array, capped at 255.
// count==256 and count==255 both return 255; caller disambiguates via c[255].
__device__ __forceinline__ int count_le_cap255(const int* c, int p) {
  int idx = 0;
#pragma unroll
  for (int step = 128; step >= 1; step >>= 1)
    idx += (c[idx + step - 1] <= p) ? step : 0;
  return idx;
}

__global__ __launch_bounds__(1024) void hist_loss_main(
    const float* __restrict__ target, const float* __restrict__ output,
    unsigned* __restrict__ part) {
  __shared__ float raw[6 * PAD];
  __shared__ int cum[6 * PAD];
  __shared__ unsigned wred[16][3];

  const int tid = threadIdx.x;

  // Phase A: cooperative load of all 6 histograms (6 x 256 f32) into LDS.
  for (int i = tid; i < 6 * KBINS; i += 1024) {
    const int a = i >> 8;   // array 0..5: even=target, odd=output
    const int j = i & 255;  // bin
    const float* src = (a & 1) ? output : target;
    raw[a * PAD + j] = src[(a >> 1) * KBINS + j];
  }
  __syncthreads();

  // Phase B: strict sequential f32 cumsum + floor (matches jnp.cumsum
  // rounding order), one lane per array; padded stride = distinct banks.
  if (tid < 6) {
    const float* r = &raw[tid * PAD];
    int* c = &cum[tid * PAD];
    float acc = 0.0f;
#pragma unroll
    for (int j = 0; j < KBINS; ++j) {
      acc += r[j];
      c[j] = (int)floorf(acc);  // acc >= 0 always
    }
  }
  __syncthreads();

  // Phase C: one pixel per thread; bisection + cross-channel carry chain.
  const int p = blockIdx.x * 1024 + tid;  // 49*1024 == N_PIX exactly
  unsigned d2[3];
  int h1 = 0, h2 = 0;
#pragma unroll
  for (int ch = 0; ch < 3; ++ch) {
    const int* cT = &cum[(2 * ch + 0) * PAD];
    const int* cO = &cum[(2 * ch + 1) * PAD];
    const int lastT = cT[255];
    const int lastO = cO[255];
    const int c1 = count_le_cap255(cT, p);
    const int c2 = count_le_cap255(cO, p);
    // s==255 exactly (c==255 AND cum[255] > p): reference never writes the
    // gap [cum[254], cum[255]) -> keep previous channel's value.
    h1 = (c1 == 255 && lastT > p) ? h1 : c1;
    h2 = (c2 == 255 && lastO > p) ? h2 : c2;
    const int d = h1 - h2;
    d2[ch] = (unsigned)(d * d);  // <= 255^2, exact
  }

  // Phase D: exact integer block reduction (wave shuffle, then cross-wave).
  const int lane = tid & 63;
  const int wave = tid >> 6;
#pragma unroll
  for (int ch = 0; ch < 3; ++ch) {
    unsigned v = d2[ch];
#pragma unroll
    for (int o = 32; o >= 1; o >>= 1) v += __shfl_down(v, o);
    if (lane == 0) wred[wave][ch] = v;
  }
  __syncthreads();
  if (tid < 3) {
    unsigned s = 0;
#pragma unroll
    for (int w = 0; w < 16; ++w) s += wred[w][tid];
    part[blockIdx.x * 3 + tid] = s;  // every ws slot written every launch
  }
}

__global__ void hist_loss_fin(const unsigned* __restrict__ part,
                              float* __restrict__ out) {
  const int b = threadIdx.x;  // 64 threads; lanes 0..48 hold one block each
  unsigned s0 = 0, s1 = 0, s2 = 0;
  if (b < 49) {
    s0 = part[b * 3 + 0];
    s1 = part[b * 3 + 1];
    s2 = part[b * 3 + 2];
  }
#pragma unroll
  for (int o = 32; o >= 1; o >>= 1) {
    s0 += __shfl_down(s0, o);
    s1 += __shfl_down(s1, o);
    s2 += __shfl_down(s2, o);
  }
  if (b == 0)
    out[0] = sqrtf((float)s0) + sqrtf((float)s1) + sqrtf((float)s2);
}

extern "C" void kernel_launch(void* const* d_in, const int* in_sizes, int n_in,
                              void* d_out, int out_size, void* d_ws,
                              size_t ws_size, hipStream_t stream) {
  const float* target = (const float*)d_in[0];  // (3,256,1) f32
  const float* output = (const float*)d_in[1];  // (3,256,1) f32
  unsigned* part = (unsigned*)d_ws;             // 49*3 u32 partials
  float* out = (float*)d_out;                   // scalar f32 loss

  hipLaunchKernelGGL(hist_loss_main, dim3(49), dim3(1024), 0, stream, target,
                     output, part);
  hipLaunchKernelGGL(hist_loss_fin, dim3(1), dim3(64), 0, stream, part, out);
}